// Round 1
// 228.865 us; speedup vs baseline: 1.0276x; 1.0276x over previous
//
#include <hip/hip_runtime.h>
#include <cmath>

#define HDIM 2048
#define H4   (HDIM / 4)         // 512 float4 per row
#define NEXP 64
#define TTOT 16384
#define KSPLIT 2
#define KBLK (HDIM / KSPLIT)    // 1024 k per block
#define BKC  64                 // k per staged chunk
#define NCHUNK (KBLK / BKC)     // 16
#define BTOK 64                 // tokens per block
#define LDT  72                 // padded k-stride (shorts); rows 16B-aligned
#define LDS_SC 65

// ws layout: [0..63] prob_acc, [64..127] gate_acc, [128..] partials
#define WS_PARTIAL_OFF 128
#define PARTIAL_FLOATS ((size_t)(TTOT / BTOK) * KSPLIT * BTOK * NEXP)  // 2.1M

typedef short  bf16x8 __attribute__((ext_vector_type(8)));
typedef float  f32x16 __attribute__((ext_vector_type(16)));

// round-to-nearest-even fp32 -> bf16 (bits, low16 zero); returns rounded value
// as fp32 so the residual (exact, Sterbenz) can be computed.
__device__ __forceinline__ unsigned bf_rn_u(float f, float* back) {
    unsigned u = __float_as_uint(f);
    unsigned r = (u + 0x7fffu + ((u >> 16) & 1u)) & 0xffff0000u;
    *back = __uint_as_float(r);
    return r;
}

// ===========================================================================
// Kernel 1: MFMA GEMM, exact 3-way bf16 split of fp32 (x = h+m+l (+~2^-23)).
// scores = hH + hM + mH + hL + mM + lH.
// Block: 64 tokens x 64 experts x K=1024 (grid 256 x 2). 4 waves, each wave
// ONE 32x32 tile via mfma_f32_32x32x16_bf16 (24 MFMA/chunk vs 48 with 16x16).
// Split: RNE for h,m; round-half-up for l; v_perm packing. fp32 partials.
// ===========================================================================
__global__ __launch_bounds__(256, 2) void router_gemm_mfma(
    const float* __restrict__ x,        // [T, H]
    const float* __restrict__ gw,       // [E, H]  (= B^T layout, E x K)
    float* __restrict__ partial,        // [256][2][64*64]
    float* __restrict__ accs)           // [128] prob/gate accumulators
{
    __shared__ short aT[3][BTOK][LDT];  // x  tile: h/m/l variants, [token][k]
    __shared__ short bT[3][NEXP][LDT];  // gw tile: h/m/l variants, [expert][k]

    const int tid  = threadIdx.x;
    const int lane = tid & 63;
    const int l31  = lane & 31;
    const int lhi  = lane >> 5;         // K-half within fragment
    const int w    = tid >> 6;          // wave 0..3
    const int wm   = w & 1;             // token half  (32 rows)
    const int wn   = w >> 1;            // expert half (32 cols)
    const int tb   = blockIdx.x;        // token block 0..255
    const int kg   = blockIdx.y;        // K half 0..1
    const int T0   = tb * BTOK;

    // zero the aux accumulators here (replaces the hipMemsetAsync dispatch);
    // gemm grid completes before router_reduce launches (stream order).
    if (tb == 0 && kg == 0 && tid < 2 * NEXP) accs[tid] = 0.0f;

    // staging role: thread t handles row t>>2, float4 cols (t&3)+4j, j=0..3
    const int srow = tid >> 2;
    const int scol = tid & 3;

    const float4* __restrict__ x4 = reinterpret_cast<const float4*>(x)
        + (size_t)(T0 + srow) * H4 + (size_t)kg * (H4 / 2) + scol;
    const float4* __restrict__ g4 = reinterpret_cast<const float4*>(gw)
        + (size_t)srow * H4 + (size_t)kg * (H4 / 2) + scol;

    f32x16 acc;
    #pragma unroll
    for (int i = 0; i < 16; ++i) acc[i] = 0.0f;

    // fragment read pointers (chunk-invariant); rows 16B-aligned (LDT=72)
    const short* aP[3];
    const short* bP[3];
    #pragma unroll
    for (int v = 0; v < 3; ++v) {
        aP[v] = &aT[v][32 * wm + l31][8 * lhi];
        bP[v] = &bT[v][32 * wn + l31][8 * lhi];
    }

    float4 xa[4], xb[4];   // prefetched fp32 chunk data (consumed before reload)

#define LOAD_CHUNK(CH) do {                                                    \
        _Pragma("unroll")                                                      \
        for (int j = 0; j < 4; ++j) {                                          \
            xa[j] = x4[(CH) * (BKC / 4) + 4 * j];                              \
            xb[j] = g4[(CH) * (BKC / 4) + 4 * j];                              \
        } } while (0)

    // split one float4 into h/m/l bf16 short4s and store to tile at [ROW][kl].
    // h,m: RNE (residuals exact via Sterbenz). l: round-half-up (+0x8000),
    // no float-back needed. Packing: v_perm grabs the two top16s in one op.
#define SPLIT_STORE(TILE, ROW, FV, JJ) do {                                    \
        const float _f[4] = {(FV).x, (FV).y, (FV).z, (FV).w};                  \
        unsigned _h[4], _m[4], _l[4];                                          \
        _Pragma("unroll")                                                      \
        for (int u = 0; u < 4; ++u) {                                          \
            float _b0, _b1;                                                    \
            _h[u] = bf_rn_u(_f[u], &_b0);                                      \
            const float _r1 = _f[u] - _b0;                                     \
            _m[u] = bf_rn_u(_r1, &_b1);                                        \
            const float _r2 = _r1 - _b1;                                       \
            _l[u] = __float_as_uint(_r2) + 0x8000u;                            \
        }                                                                      \
        const int _kl = 4 * (scol + 4 * (JJ));                                 \
        *reinterpret_cast<uint2*>(&TILE[0][ROW][_kl]) =                        \
            make_uint2(__builtin_amdgcn_perm(_h[1], _h[0], 0x07060302u),       \
                       __builtin_amdgcn_perm(_h[3], _h[2], 0x07060302u));      \
        *reinterpret_cast<uint2*>(&TILE[1][ROW][_kl]) =                        \
            make_uint2(__builtin_amdgcn_perm(_m[1], _m[0], 0x07060302u),       \
                       __builtin_amdgcn_perm(_m[3], _m[2], 0x07060302u));      \
        *reinterpret_cast<uint2*>(&TILE[2][ROW][_kl]) =                        \
            make_uint2(__builtin_amdgcn_perm(_l[1], _l[0], 0x07060302u),       \
                       __builtin_amdgcn_perm(_l[3], _l[2], 0x07060302u));      \
    } while (0)

    LOAD_CHUNK(0);

    for (int ch = 0; ch < NCHUNK; ++ch) {
        // ---- convert prefetched regs -> LDS (regs free after this) ----
        #pragma unroll
        for (int j = 0; j < 4; ++j) {
            SPLIT_STORE(aT, srow, xa[j], j);
            SPLIT_STORE(bT, srow, xb[j], j);
        }
        __syncthreads();

        if (ch + 1 < NCHUNK) LOAD_CHUNK(ch + 1);   // overlaps MFMA below

        // ---- MFMA over this chunk: 4 K=16 steps, 6 products each ----
        // A-frag: row = 32wm + (lane&31), k = 16ks + 8*(lane>>5) + 0..7
        // (NOTE: 32-row stride-144B read is 4-way bank-aliased; hidden under
        //  the MFMA pipe -- revisit with slot-XOR swizzle if MfmaUtil stalls)
        #pragma unroll
        for (int ks = 0; ks < 4; ++ks) {
            bf16x8 ah = *reinterpret_cast<const bf16x8*>(aP[0] + 16 * ks);
            bf16x8 am = *reinterpret_cast<const bf16x8*>(aP[1] + 16 * ks);
            bf16x8 al = *reinterpret_cast<const bf16x8*>(aP[2] + 16 * ks);
            bf16x8 bh = *reinterpret_cast<const bf16x8*>(bP[0] + 16 * ks);
            bf16x8 bm = *reinterpret_cast<const bf16x8*>(bP[1] + 16 * ks);
            bf16x8 bl = *reinterpret_cast<const bf16x8*>(bP[2] + 16 * ks);
            acc = __builtin_amdgcn_mfma_f32_32x32x16_bf16(ah, bh, acc, 0, 0, 0);
            acc = __builtin_amdgcn_mfma_f32_32x32x16_bf16(ah, bm, acc, 0, 0, 0);
            acc = __builtin_amdgcn_mfma_f32_32x32x16_bf16(am, bh, acc, 0, 0, 0);
            acc = __builtin_amdgcn_mfma_f32_32x32x16_bf16(ah, bl, acc, 0, 0, 0);
            acc = __builtin_amdgcn_mfma_f32_32x32x16_bf16(am, bm, acc, 0, 0, 0);
            acc = __builtin_amdgcn_mfma_f32_32x32x16_bf16(al, bh, acc, 0, 0, 0);
        }
        __syncthreads();   // LDS free for next chunk's staging
    }
#undef LOAD_CHUNK
#undef SPLIT_STORE

    // ---- write fp32 partials. 32x32 C/D layout (m74/m101):
    // col = lane&31, row = (reg&3) + 8*(reg>>2) + 4*(lane>>5)
    float* pbase = partial + ((size_t)tb * KSPLIT + kg) * (BTOK * NEXP);
    const int e = 32 * wn + l31;
    #pragma unroll
    for (int r = 0; r < 16; ++r) {
        const int t_loc = 32 * wm + (r & 3) + 8 * (r >> 2) + 4 * lhi;
        pbase[(size_t)t_loc * NEXP + e] = acc[r];
    }
}

// ===========================================================================
// Kernel 2: sum 2 K-split partials + bias, top-2 + softmax + aux partials.
// __expf for the aux-only z/ps loops; libm expf kept for output weights.
// ===========================================================================
__global__ __launch_bounds__(256) void router_reduce(
    const float* __restrict__ partial,
    const float* __restrict__ rep,
    const float* __restrict__ loads,
    const float* __restrict__ counts,
    const int*   __restrict__ total_dec,
    float* __restrict__ out_w,
    float* __restrict__ out_idx,
    float* __restrict__ prob_acc,
    float* __restrict__ gate_acc)
{
    __shared__ float sc_s[BTOK][LDS_SC];
    __shared__ float bias_s[NEXP];
    __shared__ float m_s[BTOK], zi_s[BTOK];
    __shared__ int   i1_s[BTOK], i2_s[BTOK];

    const int tid = threadIdx.x;
    const int rt  = blockIdx.x;        // 64-token tile 0..255
    const int t0  = rt * BTOK;

    if (tid < NEXP) {
        float L = logf((float)(*total_dec) + 1.0f);
        bias_s[tid] = 0.1f * rep[tid] - 0.1f * loads[tid]
                    + 0.1f * sqrtf(L / (counts[tid] + 1e-10f));
    }
    __syncthreads();

    const float* p = partial + (size_t)rt * KSPLIT * (BTOK * NEXP);
    #pragma unroll
    for (int o = 0; o < (BTOK * NEXP) / 256; ++o) {
        const int idx = o * 256 + tid;
        float s = p[idx] + p[BTOK * NEXP + idx];
        sc_s[idx >> 6][idx & 63] = s + bias_s[idx & 63];
    }
    __syncthreads();

    // pass 1: per-token top-2 (strict '>' keeps lowest index), softmax weights
    if (tid < BTOK) {
        const int t = tid;
        float m1 = -INFINITY, m2 = -INFINITY;
        int   i1 = 0, i2 = 0;
        for (int e = 0; e < NEXP; ++e) {
            const float s = sc_s[t][e];
            if (s > m1)      { m2 = m1; i2 = i1; m1 = s; i1 = e; }
            else if (s > m2) { m2 = s; i2 = e; }
        }
        float z = 0.0f;
        for (int e = 0; e < NEXP; ++e) z += __expf(sc_s[t][e] - m1);

        const float e2  = expf(m2 - m1);
        const float inv = 1.0f / (1.0f + e2);
        const int   gt  = t0 + t;
        reinterpret_cast<float2*>(out_w)[gt]   = make_float2(inv, e2 * inv);
        reinterpret_cast<float2*>(out_idx)[gt] = make_float2((float)i1, (float)i2);
        m_s[t] = m1; zi_s[t] = 1.0f / z; i1_s[t] = i1; i2_s[t] = i2;
    }
    __syncthreads();

    // pass 2: per-expert partial sums for aux loss
    if (tid < NEXP) {
        const int e = tid;
        float ps = 0.0f, gs = 0.0f;
        for (int t = 0; t < BTOK; ++t) {
            ps += __expf(sc_s[t][e] - m_s[t]) * zi_s[t];
            gs += (float)((i1_s[t] == e) + (i2_s[t] == e));
        }
        atomicAdd(&prob_acc[e], ps);
        atomicAdd(&gate_acc[e], gs);
    }
}

// ===========================================================================
// Fallback (round-1/3 proven): single fused fp32 kernel, if ws too small.
// ===========================================================================
#define BKF  32
#define LDAF (64 + 4)
__global__ __launch_bounds__(256) void router_main(
    const float* __restrict__ x,
    const float* __restrict__ gw,
    const float* __restrict__ rep,
    const float* __restrict__ loads,
    const float* __restrict__ counts,
    const int*   __restrict__ total_dec,
    float* __restrict__ out_w,
    float* __restrict__ out_idx,
    float* __restrict__ prob_acc,
    float* __restrict__ gate_acc)
{
    __shared__ float a_s[2][BKF][LDAF];
    __shared__ float b_s[2][BKF][LDAF];
    __shared__ float sc_s[64][LDS_SC];
    __shared__ float bias_s[NEXP];
    __shared__ float m_s[64], z_s[64];
    __shared__ int   i1_s[64], i2_s[64];

    const int tid = threadIdx.x;
    const int tx  = tid & 15;
    const int ty  = tid >> 4;
    const int r0  = tid >> 3;
    const int c4  = tid & 7;
    const int t0  = blockIdx.x * 64;

    if (tid < NEXP) {
        float L = logf((float)(*total_dec) + 1.0f);
        bias_s[tid] = 0.1f * rep[tid] - 0.1f * loads[tid]
                    + 0.1f * sqrtf(L / (counts[tid] + 1e-10f));
    }

    const float4* __restrict__ x4 = reinterpret_cast<const float4*>(x) + (size_t)t0 * H4;
    const float4* __restrict__ g4 = reinterpret_cast<const float4*>(gw);

    float acc[4][4] = {};

#define STORE_TILE(BUFI, A0, A1, B0, B1) do {                                  \
        float _t0[4] = {(A0).x, (A0).y, (A0).z, (A0).w};                       \
        float _t1[4] = {(A1).x, (A1).y, (A1).z, (A1).w};                       \
        float _t2[4] = {(B0).x, (B0).y, (B0).z, (B0).w};                       \
        float _t3[4] = {(B1).x, (B1).y, (B1).z, (B1).w};                       \
        _Pragma("unroll")                                                      \
        for (int u = 0; u < 4; ++u) {                                          \
            a_s[BUFI][c4 * 4 + u][r0]      = _t0[u];                           \
            a_s[BUFI][c4 * 4 + u][r0 + 32] = _t1[u];                           \
            b_s[BUFI][c4 * 4 + u][r0]      = _t2[u];                           \
            b_s[BUFI][c4 * 4 + u][r0 + 32] = _t3[u];                           \
        } } while (0)

    {
        float4 a0 = x4[(size_t)r0 * H4 + c4];
        float4 a1 = x4[(size_t)(r0 + 32) * H4 + c4];
        float4 b0 = g4[(size_t)r0 * H4 + c4];
        float4 b1 = g4[(size_t)(r0 + 32) * H4 + c4];
        STORE_TILE(0, a0, a1, b0, b1);
    }
    __syncthreads();

    int buf = 0;
    for (int it = 0; it < HDIM / BKF; ++it) {
        float4 na0, na1, nb0, nb1;
        const bool has_next = (it + 1 < HDIM / BKF);
        if (has_next) {
            const int k4 = (it + 1) * (BKF / 4);
            na0 = x4[(size_t)r0 * H4 + k4 + c4];
            na1 = x4[(size_t)(r0 + 32) * H4 + k4 + c4];
            nb0 = g4[(size_t)r0 * H4 + k4 + c4];
            nb1 = g4[(size_t)(r0 + 32) * H4 + k4 + c4];
        }
        #pragma unroll
        for (int kk = 0; kk < BKF; ++kk) {
            const float4 afv = *reinterpret_cast<const float4*>(&a_s[buf][kk][ty * 4]);
            const float4 bfv = *reinterpret_cast<const float4*>(&b_s[buf][kk][tx * 4]);
            const float af[4] = {afv.x, afv.y, afv.z, afv.w};
            const float bf[4] = {bfv.x, bfv.y, bfv.z, bfv.w};
            #pragma unroll
            for (int i = 0; i < 4; ++i)
                #pragma unroll
                for (int j = 0; j < 4; ++j)
                    acc[i][j] = fmaf(af[i], bf[j], acc[i][j]);
        }
        if (has_next) STORE_TILE(buf ^ 1, na0, na1, nb0, nb1);
        __syncthreads();
        buf ^= 1;
    }
#undef STORE_TILE

    #pragma unroll
    for (int i = 0; i < 4; ++i)
        #pragma unroll
        for (int j = 0; j < 4; ++j)
            sc_s[ty * 4 + i][tx * 4 + j] = acc[i][j] + bias_s[tx * 4 + j];
    __syncthreads();

    if (tid < 64) {
        const int t = tid;
        float m1 = -INFINITY, m2 = -INFINITY;
        int   i1 = 0, i2 = 0;
        for (int e = 0; e < NEXP; ++e) {
            const float s = sc_s[t][e];
            if (s > m1)      { m2 = m1; i2 = i1; m1 = s; i1 = e; }
            else if (s > m2) { m2 = s; i2 = e; }
        }
        float z = 0.0f;
        for (int e = 0; e < NEXP; ++e) z += expf(sc_s[t][e] - m1);
        const float e2  = expf(m2 - m1);
        const float inv = 1.0f / (1.0f + e2);
        const int   gt  = t0 + t;
        reinterpret_cast<float2*>(out_w)[gt]   = make_float2(inv, e2 * inv);
        reinterpret_cast<float2*>(out_idx)[gt] = make_float2((float)i1, (float)i2);
        m_s[t] = m1; z_s[t] = z; i1_s[t] = i1; i2_s[t] = i2;
    }
    __syncthreads();

    if (tid < NEXP) {
        const int e = tid;
        float ps = 0.0f, gs = 0.0f;
        for (int t = 0; t < 64; ++t) {
            ps += expf(sc_s[t][e] - m_s[t]) / z_s[t];
            gs += (float)((i1_s[t] == e) + (i2_s[t] == e));
        }
        atomicAdd(&prob_acc[e], ps);
        atomicAdd(&gate_acc[e], gs);
    }
}

__global__ void router_aux(const float* __restrict__ prob_acc,
                           const float* __restrict__ gate_acc,
                           float* __restrict__ out_aux)
{
    const float invT = 1.0f / (float)TTOT;
    const int e = threadIdx.x;
    float v = (gate_acc[e] * invT) * (prob_acc[e] * invT);
    #pragma unroll
    for (int off = 32; off > 0; off >>= 1)
        v += __shfl_down(v, off);
    if (e == 0) out_aux[0] = v * (float)NEXP;
}

extern "C" void kernel_launch(void* const* d_in, const int* in_sizes, int n_in,
                              void* d_out, int out_size, void* d_ws, size_t ws_size,
                              hipStream_t stream)
{
    const float* x      = (const float*)d_in[0];
    const float* gw     = (const float*)d_in[1];
    const float* rep    = (const float*)d_in[2];
    const float* loads  = (const float*)d_in[3];
    const float* counts = (const float*)d_in[4];
    const int*   total  = (const int*)d_in[5];

    float* out     = (float*)d_out;
    float* out_w   = out;            // [16384*2] routing weights
    float* out_idx = out + 32768;    // [16384*2] expert indices as float
    float* out_aux = out + 65536;    // [1] aux loss

    float* prob_acc = (float*)d_ws;
    float* gate_acc = prob_acc + NEXP;
    float* partial  = (float*)d_ws + WS_PARTIAL_OFF;

    const size_t ws_needed = (WS_PARTIAL_OFF + PARTIAL_FLOATS) * sizeof(float);

    if (ws_size >= ws_needed) {
        // accumulator zeroing is folded into router_gemm_mfma block (0,0)
        router_gemm_mfma<<<dim3(TTOT / BTOK, KSPLIT), dim3(256), 0, stream>>>(
            x, gw, partial, prob_acc);
        router_reduce<<<dim3(TTOT / BTOK), dim3(256), 0, stream>>>(
            partial, rep, loads, counts, total, out_w, out_idx, prob_acc, gate_acc);
    } else {
        hipMemsetAsync(d_ws, 0, WS_PARTIAL_OFF * sizeof(float), stream);
        router_main<<<dim3(TTOT / 64), dim3(256), 0, stream>>>(
            x, gw, rep, loads, counts, total, out_w, out_idx, prob_acc, gate_acc);
    }
    router_aux<<<dim3(1), dim3(64), 0, stream>>>(prob_acc, gate_acc, out_aux);
}